// Round 7
// baseline (674.336 us; speedup 1.0000x reference)
//
#include <hip/hip_runtime.h>
#include <hip/hip_bf16.h>

#define D 128
#define N_TAXON 100000
#define N_SOTU 200000
#define E_HP 200000
#define E_RH 2000000
#define OUTC 64
#define NBUCK 25      // ceil(N_SOTU / 8192)
#define BSHIFT 13

typedef __hip_bfloat16 bf16;
typedef __bf16 bf16v8 __attribute__((ext_vector_type(8)));
typedef float f32x4 __attribute__((ext_vector_type(4)));
typedef int i32x4 __attribute__((ext_vector_type(4)));
typedef unsigned u32x2 __attribute__((ext_vector_type(2)));

union Frag { i32x4 i; bf16v8 v; };

__device__ __forceinline__ float bflo(unsigned u) { return __uint_as_float(u << 16); }
__device__ __forceinline__ float bfhi(unsigned u) { return __uint_as_float(u & 0xffff0000u); }

__device__ __forceinline__ unsigned short f2bf(float x) {
    unsigned u = __float_as_uint(x);
    unsigned r = (u + 0x7fffu + ((u >> 16) & 1u)) >> 16;   // round-to-nearest-even
    return (unsigned short)r;
}
__device__ __forceinline__ unsigned packbf(float a, float b) {
    return (unsigned)f2bf(a) | ((unsigned)f2bf(b) << 16);
}

// a-frag (weight) read straight from the pre-swizzled global image.
// col = 16*cf_abs + ln; frag covers Wt[col][32ks+8g .. +7]
__device__ __forceinline__ i32x4 ldWfrag(const unsigned short* __restrict__ Wt,
                                         int col, int ks, int g) {
    int off = ((col << 8) + (ks << 6) + (g << 4)) ^ ((col & 7) << 4);
    return *(const i32x4*)((const char*)Wt + off);
}

// ---------------- fused: hp degree + rh bucket histogram + bucket prefix ----------------
__global__ __launch_bounds__(256) void countAll_kernel(const int* __restrict__ hp_dst,
                                                       const int* __restrict__ rh_dst,
                                                       unsigned* __restrict__ cnt_t,
                                                       unsigned* __restrict__ bcnt,
                                                       unsigned* __restrict__ bcursor,
                                                       unsigned* __restrict__ ticket)
{
    __shared__ unsigned hist[NBUCK];
    for (int i = threadIdx.x; i < NBUCK; i += 256) hist[i] = 0;
    __syncthreads();
    int stride = gridDim.x * 256;
    for (int e = blockIdx.x * 256 + threadIdx.x; e < E_HP; e += stride)
        atomicAdd(&cnt_t[hp_dst[e]], 1u);
    for (int e = blockIdx.x * 256 + threadIdx.x; e < E_RH; e += stride)
        atomicAdd(&hist[rh_dst[e] >> BSHIFT], 1u);
    __syncthreads();
    if (threadIdx.x < NBUCK) atomicAdd(&bcnt[threadIdx.x], hist[threadIdx.x]);
    __syncthreads();
    if (threadIdx.x == 0) {
        __threadfence();
        unsigned t = atomicAdd(ticket, 1u);
        if (t == gridDim.x - 1) {        // last block: 25-entry exclusive prefix
            unsigned acc = 0;
            for (int b = 0; b < NBUCK; ++b) {
                unsigned v = atomicAdd(&bcnt[b], 0u);   // coherent read
                bcursor[b] = acc; acc += v;
            }
        }
    }
}

// ---------------- rh: partition edges into dst-buckets + per-dst count ----------------
__global__ __launch_bounds__(256) void partition_kernel(
    const int* __restrict__ src, const int* __restrict__ dst,
    unsigned* __restrict__ bcursor, unsigned* __restrict__ cnt_s,
    unsigned long long* __restrict__ ebuf, int n)
{
    __shared__ unsigned hist[NBUCK];
    __shared__ unsigned lcur[NBUCK];
    int base = blockIdx.x * 2048;
    for (int i = threadIdx.x; i < NBUCK; i += 256) hist[i] = 0;
    __syncthreads();
    int s[8], d[8];
#pragma unroll
    for (int k = 0; k < 8; ++k) {
        int e = base + k * 256 + threadIdx.x;
        if (e < n) {
            s[k] = src[e]; d[k] = dst[e];
            atomicAdd(&hist[d[k] >> BSHIFT], 1u);
            atomicAdd(&cnt_s[d[k]], 1u);
        } else d[k] = -1;
    }
    __syncthreads();
    if (threadIdx.x < NBUCK)
        lcur[threadIdx.x] = atomicAdd(&bcursor[threadIdx.x], hist[threadIdx.x]);
    __syncthreads();
#pragma unroll
    for (int k = 0; k < 8; ++k) {
        if (d[k] >= 0) {
            unsigned slot = atomicAdd(&lcur[d[k] >> BSHIFT], 1u);
            ebuf[slot] = ((unsigned long long)(unsigned)d[k] << 32) | (unsigned)s[k];
        }
    }
}

// ---------------- combined 3-phase exclusive scan over [cnt_t ; cnt_s] ----------------
__global__ __launch_bounds__(256) void scanA_kernel(const unsigned* __restrict__ cnt,
                                                    unsigned* __restrict__ bsum, int n)
{
    int lane = threadIdx.x & 63, wv = threadIdx.x >> 6;
    __shared__ unsigned ws[4];
    int i = blockIdx.x * 256 + threadIdx.x;
    unsigned v = (i < n) ? cnt[i] : 0u;
    for (int off = 1; off < 64; off <<= 1) v += __shfl_xor(v, off, 64);
    if (lane == 0) ws[wv] = v;
    __syncthreads();
    if (threadIdx.x == 0) bsum[blockIdx.x] = ws[0] + ws[1] + ws[2] + ws[3];
}

// handles nb <= 2048 (2 elements per thread)
__global__ __launch_bounds__(1024) void scanB_kernel(unsigned* __restrict__ bsum, int nb,
                                                     unsigned* __restrict__ total_out)
{
    int lane = threadIdx.x & 63, wv = threadIdx.x >> 6;
    __shared__ unsigned wsum[16];
    int t = threadIdx.x;
    unsigned v0 = (2 * t     < nb) ? bsum[2 * t]     : 0u;
    unsigned v1 = (2 * t + 1 < nb) ? bsum[2 * t + 1] : 0u;
    unsigned v = v0 + v1;
    unsigned s = v;
    for (int off = 1; off < 64; off <<= 1) {
        unsigned tt = __shfl_up(s, off, 64);
        if (lane >= off) s += tt;
    }
    if (lane == 63) wsum[wv] = s;
    __syncthreads();
    unsigned woff = 0, tot = 0;
    for (int w = 0; w < 16; ++w) { if (w < wv) woff += wsum[w]; tot += wsum[w]; }
    unsigned ex = woff + s - v;
    if (2 * t     < nb) bsum[2 * t]     = ex;
    if (2 * t + 1 < nb) bsum[2 * t + 1] = ex + v0;
    if (t == 0) *total_out = tot;
}

__global__ __launch_bounds__(256) void scanC_kernel(const unsigned* __restrict__ cnt,
                                                    const unsigned* __restrict__ bsum,
                                                    unsigned* __restrict__ row_ptr,
                                                    unsigned* __restrict__ cursor, int n)
{
    int lane = threadIdx.x & 63, wv = threadIdx.x >> 6;
    __shared__ unsigned wsum[4];
    int i = blockIdx.x * 256 + threadIdx.x;
    unsigned v = (i < n) ? cnt[i] : 0u;
    unsigned s = v;
    for (int off = 1; off < 64; off <<= 1) {
        unsigned t = __shfl_up(s, off, 64);
        if (lane >= off) s += t;
    }
    if (lane == 63) wsum[wv] = s;
    __syncthreads();
    unsigned woff = bsum[blockIdx.x];
    for (int w = 0; w < wv; ++w) woff += wsum[w];
    if (i < n) { unsigned p = woff + s - v; row_ptr[i] = p; cursor[i] = p; }
}

// ---------------- fused CSR fills (hp raw edges + rh from ebuf) ----------------
__global__ __launch_bounds__(256) void fills_kernel(const int* __restrict__ hp_src,
                                                    const int* __restrict__ hp_dst,
                                                    const unsigned long long* __restrict__ ebuf,
                                                    unsigned* __restrict__ cursor,
                                                    int* __restrict__ sorted_all)
{
    int stride = gridDim.x * 256;
    for (int i = blockIdx.x * 256 + threadIdx.x; i < E_HP + E_RH; i += stride) {
        if (i < E_HP) {
            unsigned pos = atomicAdd(&cursor[hp_dst[i]], 1u);
            sorted_all[pos] = hp_src[i];
        } else {
            unsigned long long v = ebuf[i - E_HP];
            unsigned pos = atomicAdd(&cursor[N_TAXON + (unsigned)(v >> 32)], 1u);
            sorted_all[pos] = (int)(unsigned)v;
        }
    }
}

// ---------------- all weights: transpose + bf16 + XOR-swizzle in one kernel ----------------
__global__ __launch_bounds__(256) void wprep_all_kernel(
    const float* __restrict__ W1l, const float* __restrict__ W1r,
    const float* __restrict__ W2l, const float* __restrict__ W2r,
    const float* __restrict__ W3l, const float* __restrict__ W3r,
    const float* __restrict__ Wlin, unsigned short* __restrict__ wtbase)
{
    int e = blockIdx.x * 256 + threadIdx.x;
    if (e >= 6 * 16384 + 8192) return;
    const float* srcs[7] = { W1l, W1r, W2l, W2r, W3l, W3r, Wlin };
    int m = e >> 14;                       // 0..5 for the 128x128s, 6 for Wlin
    int local = (m < 6) ? (e & 16383) : (e - 98304);
    int N = (m < 6) ? 128 : 64;
    int k = local / N, col = local - k * N;
    unsigned short* dst = wtbase + ((m < 6) ? m * 16384 : 98304);
    dst[(col * 128 + k) ^ ((col & 7) << 3)] = f2bf(srcs[m][local]);
}

// ---------------- triple GEMM: y1 = X@W1l, z1 = X@W1r, y2 = X@W2l (one X pass) ----------------
// weights read from global (L2-resident swizzled images); no LDS
__global__ __launch_bounds__(256) void gemm3_kernel(
    const float* __restrict__ X,
    const unsigned short* __restrict__ WtA, const unsigned short* __restrict__ WtB,
    const unsigned short* __restrict__ WtC,
    unsigned* __restrict__ Ya, unsigned* __restrict__ Yb,
    unsigned* __restrict__ Yc /* Y23 half-a (IL=2) */, int M)
{
    int wave = threadIdx.x >> 6, lane = threadIdx.x & 63;
    int ln = lane & 15, g = lane >> 4;
    int row = blockIdx.x * 64 + wave * 16 + ln;
    int rl = row < M ? row : M - 1;

    f32x4 accA[8], accB[8], accC[8];
#pragma unroll
    for (int cf = 0; cf < 8; ++cf)
        for (int e = 0; e < 4; ++e) { accA[cf][e] = 0.f; accB[cf][e] = 0.f; accC[cf][e] = 0.f; }

    const f32x4* xr = (const f32x4*)(X + (size_t)rl * 128);
#pragma unroll
    for (int ks = 0; ks < 4; ++ks) {
        f32x4 fa = xr[ks * 8 + g * 2];
        f32x4 fb = xr[ks * 8 + g * 2 + 1];
        Frag xf;
        i32x4 t = { (int)packbf(fa.x, fa.y), (int)packbf(fa.z, fa.w),
                    (int)packbf(fb.x, fb.y), (int)packbf(fb.z, fb.w) };
        xf.i = t;
#pragma unroll
        for (int cf = 0; cf < 8; ++cf) {
            int col = cf * 16 + ln;
            Frag wa; wa.i = ldWfrag(WtA, col, ks, g);
            Frag wb; wb.i = ldWfrag(WtB, col, ks, g);
            Frag wc; wc.i = ldWfrag(WtC, col, ks, g);
            accA[cf] = __builtin_amdgcn_mfma_f32_16x16x32_bf16(wa.v, xf.v, accA[cf], 0, 0, 0);
            accB[cf] = __builtin_amdgcn_mfma_f32_16x16x32_bf16(wb.v, xf.v, accB[cf], 0, 0, 0);
            accC[cf] = __builtin_amdgcn_mfma_f32_16x16x32_bf16(wc.v, xf.v, accC[cf], 0, 0, 0);
        }
    }

    if (row < M) {
        unsigned* ra = Ya + (size_t)row * 64;
        unsigned* rb = Yb + (size_t)row * 64;
        unsigned* rc = Yc + (size_t)row * 128;
#pragma unroll
        for (int cf = 0; cf < 8; ++cf) {
            int p = cf * 8 + g * 2;
            u32x2 oa, ob;
            oa.x = packbf(accA[cf][0], accA[cf][1]); oa.y = packbf(accA[cf][2], accA[cf][3]);
            ob.x = packbf(accB[cf][0], accB[cf][1]); ob.y = packbf(accB[cf][2], accB[cf][3]);
            *(u32x2*)(ra + p) = oa;
            *(u32x2*)(rb + p) = ob;
            rc[p * 2]       = packbf(accC[cf][0], accC[cf][1]);
            rc[(p + 1) * 2] = packbf(accC[cf][2], accC[cf][3]);
        }
    }
}

// ---------------- MFMA GEMM (LDS-staged weights) — used for z2 = x_sotu @ W2r ----------------
__global__ __launch_bounds__(256) void gemmS_kernel(
    const float* __restrict__ Xin, const unsigned short* __restrict__ Wt,
    unsigned* __restrict__ Yout, int M)
{
    __shared__ char sW[32768];
    for (int c = threadIdx.x; c < 2048; c += 256)
        ((i32x4*)sW)[c] = ((const i32x4*)Wt)[c];
    __syncthreads();

    int wave = threadIdx.x >> 6, lane = threadIdx.x & 63;
    int ln = lane & 15, g = lane >> 4;
    int row = blockIdx.x * 64 + wave * 16 + ln;
    int rl = row < M ? row : M - 1;
    int swz = (ln & 7) << 4;

    f32x4 acc[8];
#pragma unroll
    for (int cf = 0; cf < 8; ++cf)
        for (int e = 0; e < 4; ++e) acc[cf][e] = 0.0f;

    const f32x4* xr = (const f32x4*)(Xin + (size_t)rl * 128);
#pragma unroll
    for (int ks = 0; ks < 4; ++ks) {
        f32x4 fa = xr[ks * 8 + g * 2];
        f32x4 fb = xr[ks * 8 + g * 2 + 1];
        Frag xf;
        i32x4 t = { (int)packbf(fa.x, fa.y), (int)packbf(fa.z, fa.w),
                    (int)packbf(fb.x, fb.y), (int)packbf(fb.z, fb.w) };
        xf.i = t;
#pragma unroll
        for (int cf = 0; cf < 8; ++cf) {
            Frag wf;
            wf.i = *(const i32x4*)(sW + ((((cf * 16 + ln) << 8) + (ks << 6) + (g << 4)) ^ swz));
            acc[cf] = __builtin_amdgcn_mfma_f32_16x16x32_bf16(wf.v, xf.v, acc[cf], 0, 0, 0);
        }
    }

    if (row < M) {
        unsigned* orow = Yout + (size_t)row * 64;
#pragma unroll
        for (int cf = 0; cf < 8; ++cf) {
            u32x2 o;
            o.x = packbf(acc[cf][0], acc[cf][1]);
            o.y = packbf(acc[cf][2], acc[cf][3]);
            *(u32x2*)(orow + cf * 8 + g * 2) = o;
        }
    }
}

// ---------------- fused layer-1 agg + W3l GEMM -> Y23 half-b ----------------
// block = 16 taxon rows; wave v gathers rows 4v..4v+3 -> LDS tile -> MFMA
__global__ __launch_bounds__(256) void aggGemm1_kernel(
    const unsigned* __restrict__ Y /*y1*/, const unsigned* __restrict__ rp,
    const int* __restrict__ nbr, const unsigned* __restrict__ Z /*z1*/,
    const float* __restrict__ bias /*b1*/,
    const unsigned short* __restrict__ Wt /*W3l*/,
    unsigned* __restrict__ Y23, int nrows)
{
    __shared__ unsigned ht[16 * 64];
    int wave = threadIdx.x >> 6, lane = threadIdx.x & 63;
    int rbase = blockIdx.x * 16;
    float2 b2 = ((const float2*)bias)[lane];

    for (int i = 0; i < 4; ++i) {
        int rloc = wave * 4 + i;
        int r = rbase + rloc;
        unsigned beg = rp[r], end = rp[r + 1];
        float a0 = 0.f, a1 = 0.f;
        unsigned u = beg;
        for (; u + 2 <= end; u += 2) {
            int j0 = nbr[u], j1 = nbr[u + 1];
            unsigned p0 = Y[(size_t)j0 * 64 + lane];
            unsigned p1 = Y[(size_t)j1 * 64 + lane];
            a0 += bflo(p0) + bflo(p1);
            a1 += bfhi(p0) + bfhi(p1);
        }
        if (u < end) {
            unsigned p = Y[(size_t)nbr[u] * 64 + lane];
            a0 += bflo(p); a1 += bfhi(p);
        }
        unsigned c = end - beg;
        float inv = 1.f / (float)(c ? c : 1u);
        unsigned zp = Z[(size_t)r * 64 + lane];
        ht[(rloc * 64 + lane) ^ ((rloc & 7) << 2)] =
            packbf(fmaxf(a0 * inv + bflo(zp) + b2.x, 0.f),
                   fmaxf(a1 * inv + bfhi(zp) + b2.y, 0.f));
    }
    __syncthreads();

    int ln = lane & 15, g = lane >> 4;
    f32x4 acc[2];
#pragma unroll
    for (int cf = 0; cf < 2; ++cf) for (int e = 0; e < 4; ++e) acc[cf][e] = 0.f;
#pragma unroll
    for (int ks = 0; ks < 4; ++ks) {
        Frag xf; xf.i = *(const i32x4*)&ht[(ln * 64 + ks * 16 + g * 4) ^ ((ln & 7) << 2)];
#pragma unroll
        for (int cf = 0; cf < 2; ++cf) {
            int col = wave * 32 + cf * 16 + ln;
            Frag wf; wf.i = ldWfrag(Wt, col, ks, g);
            acc[cf] = __builtin_amdgcn_mfma_f32_16x16x32_bf16(wf.v, xf.v, acc[cf], 0, 0, 0);
        }
    }
    unsigned* orow = Y23 + (size_t)(rbase + ln) * 128 + 1;
#pragma unroll
    for (int cf = 0; cf < 2; ++cf) {
        int p = wave * 16 + cf * 8 + g * 2;
        orow[p * 2]       = packbf(acc[cf][0], acc[cf][1]);
        orow[(p + 1) * 2] = packbf(acc[cf][2], acc[cf][3]);
    }
}

// ---------------- fused rh agg + W3r(+m3+b3,relu) + Wlin(+blin) -> f32 out ----------------
// block = 16 sotu rows; wave v gathers rows 4v..4v+3
__global__ __launch_bounds__(256) void aggGemm23_kernel(
    const unsigned* __restrict__ Y23, const unsigned* __restrict__ rp,
    const int* __restrict__ nbr, const unsigned* __restrict__ Z /*z2*/,
    const float* __restrict__ b2, const float* __restrict__ b3,
    const float* __restrict__ blin,
    const unsigned short* __restrict__ Wt3r, const unsigned short* __restrict__ Wtlin,
    float* __restrict__ out, int nrows)
{
    __shared__ unsigned sh[16 * 64];   // sotu_h tile (bf16 pairs, swizzled)
    __shared__ unsigned sm[16 * 64];   // mean3 tile
    __shared__ unsigned s2[16 * 64];   // h2 tile
    int wave = threadIdx.x >> 6, lane = threadIdx.x & 63;
    int rbase = blockIdx.x * 16;
    float2 bv2 = ((const float2*)b2)[lane];

    for (int i = 0; i < 4; ++i) {
        int rloc = wave * 4 + i;
        int r = rbase + rloc;
        unsigned beg = rp[r], end = rp[r + 1];
        float a0 = 0.f, a1 = 0.f, a2 = 0.f, a3 = 0.f;
        unsigned u = beg;
        for (; u + 2 <= end; u += 2) {
            int j0 = nbr[u], j1 = nbr[u + 1];
            u32x2 A = *(const u32x2*)(Y23 + (size_t)j0 * 128 + lane * 2);
            u32x2 B = *(const u32x2*)(Y23 + (size_t)j1 * 128 + lane * 2);
            a0 += bflo(A.x) + bflo(B.x); a1 += bfhi(A.x) + bfhi(B.x);
            a2 += bflo(A.y) + bflo(B.y); a3 += bfhi(A.y) + bfhi(B.y);
        }
        if (u < end) {
            u32x2 A = *(const u32x2*)(Y23 + (size_t)nbr[u] * 128 + lane * 2);
            a0 += bflo(A.x); a1 += bfhi(A.x); a2 += bflo(A.y); a3 += bfhi(A.y);
        }
        unsigned c = end - beg;
        float inv = 1.f / (float)(c ? c : 1u);
        unsigned zp = Z[(size_t)r * 64 + lane];
        int idx = (rloc * 64 + lane) ^ ((rloc & 7) << 2);
        sh[idx] = packbf(fmaxf(a0 * inv + bflo(zp) + bv2.x, 0.f),
                         fmaxf(a1 * inv + bfhi(zp) + bv2.y, 0.f));
        sm[idx] = packbf(a2 * inv, a3 * inv);
    }
    __syncthreads();

    int ln = lane & 15, g = lane >> 4;
    // stage 1: h2 = relu(sotu_h @ W3r + m3 + b3); wave covers cols 32*wave .. +31
    f32x4 acc[2];
#pragma unroll
    for (int cf = 0; cf < 2; ++cf) for (int e = 0; e < 4; ++e) acc[cf][e] = 0.f;
#pragma unroll
    for (int ks = 0; ks < 4; ++ks) {
        Frag xf; xf.i = *(const i32x4*)&sh[(ln * 64 + ks * 16 + g * 4) ^ ((ln & 7) << 2)];
#pragma unroll
        for (int cf = 0; cf < 2; ++cf) {
            int col = wave * 32 + cf * 16 + ln;
            Frag wf; wf.i = ldWfrag(Wt3r, col, ks, g);
            acc[cf] = __builtin_amdgcn_mfma_f32_16x16x32_bf16(wf.v, xf.v, acc[cf], 0, 0, 0);
        }
    }
#pragma unroll
    for (int cf = 0; cf < 2; ++cf) {
        int c0 = wave * 32 + cf * 16 + g * 4;
        int idx = (ln * 64 + (c0 >> 1)) ^ ((ln & 7) << 2);
        u32x2 mp = *(const u32x2*)&sm[idx];
        f32x4 bb = *(const f32x4*)(b3 + c0);
        float o0 = fmaxf(acc[cf][0] + bflo(mp.x) + bb.x, 0.f);
        float o1 = fmaxf(acc[cf][1] + bfhi(mp.x) + bb.y, 0.f);
        float o2 = fmaxf(acc[cf][2] + bflo(mp.y) + bb.z, 0.f);
        float o3 = fmaxf(acc[cf][3] + bfhi(mp.y) + bb.w, 0.f);
        u32x2 o; o.x = packbf(o0, o1); o.y = packbf(o2, o3);
        *(u32x2*)&s2[idx] = o;
    }
    __syncthreads();

    // stage 2: out = h2 @ Wlin + blin; wave covers cols 16*wave .. +15
    f32x4 accL = *(const f32x4*)(blin + wave * 16 + g * 4);
#pragma unroll
    for (int ks = 0; ks < 4; ++ks) {
        Frag xf; xf.i = *(const i32x4*)&s2[(ln * 64 + ks * 16 + g * 4) ^ ((ln & 7) << 2)];
        int col = wave * 16 + ln;
        Frag wf; wf.i = ldWfrag(Wtlin, col, ks, g);
        accL = __builtin_amdgcn_mfma_f32_16x16x32_bf16(wf.v, xf.v, accL, 0, 0, 0);
    }
    *(f32x4*)(out + (size_t)(rbase + ln) * 64 + wave * 16 + g * 4) = accL;
}

extern "C" void kernel_launch(void* const* d_in, const int* in_sizes, int n_in,
                              void* d_out, int out_size, void* d_ws, size_t ws_size,
                              hipStream_t stream)
{
    const float* x_taxon = (const float*)d_in[0];
    const float* x_sotu  = (const float*)d_in[1];
    const int* hp_src = (const int*)d_in[2];
    const int* hp_dst = (const int*)d_in[3];
    const int* rh_src = (const int*)d_in[4];
    const int* rh_dst = (const int*)d_in[5];
    const float* W1l = (const float*)d_in[6];
    const float* W1r = (const float*)d_in[7];
    const float* b1  = (const float*)d_in[8];
    const float* W2l = (const float*)d_in[9];
    const float* W2r = (const float*)d_in[10];
    const float* b2  = (const float*)d_in[11];
    const float* W3l = (const float*)d_in[12];
    const float* W3r = (const float*)d_in[13];
    const float* b3  = (const float*)d_in[14];
    const float* Wlin = (const float*)d_in[15];
    const float* blin = (const float*)d_in[16];
    float* out = (float*)d_out;

    // ---- workspace layout (bytes) ----
    char* ws = (char*)d_ws;
    unsigned* Y23      = (unsigned*)(ws);                 // [100K][128] interleaved (y2|y3)
    unsigned* z2       = (unsigned*)(ws + 51200000);      // [200K][64]
    unsigned* y1       = (unsigned*)(ws + 102400000);     // [100K][64]
    unsigned* z1       = (unsigned*)(ws + 128000000);     // [100K][64]
    unsigned long long* ebuf = (unsigned long long*)(ws + 153600000);  // 16MB
    int*      sorted_all = (int*)(ws + 179200000);        // [E_HP + E_RH] = 8.8MB
    unsigned* row_ptr  = (unsigned*)(ws + 188000000);     // [300001]
    unsigned* cursor   = (unsigned*)(ws + 189200128);     // [300000]
    unsigned* cnt      = (unsigned*)(ws + 190400128);     // [300000]  (cnt_t ; cnt_s)
    unsigned* bcnt     = (unsigned*)(ws + 191600128);     // [32]
    unsigned* bcursor  = (unsigned*)(ws + 191600256);     // [32]; bcursor[31] = ticket
    unsigned* bsum     = (unsigned*)(ws + 191600384);     // [2048]
    unsigned short* wtbase = (unsigned short*)(ws + 191608576);  // 7 swizzled images
    unsigned* cnt_t = cnt;
    unsigned* cnt_s = cnt + N_TAXON;
    unsigned* row_ptr_t = row_ptr;
    unsigned* row_ptr_s = row_ptr + N_TAXON;
    unsigned* ticket = bcursor + 31;
    unsigned short* Wt1l = wtbase;
    unsigned short* Wt1r = wtbase + 16384;
    unsigned short* Wt2l = wtbase + 32768;
    unsigned short* Wt2r = wtbase + 49152;
    unsigned short* Wt3l = wtbase + 65536;
    unsigned short* Wt3r = wtbase + 81920;
    unsigned short* Wtlin = wtbase + 98304;

    // zero cnt + bcnt + bcursor(incl. ticket)
    hipMemsetAsync(cnt, 0, 300000 * 4 + 256, stream);

    // ---- CSR build ----
    countAll_kernel<<<1024, 256, 0, stream>>>(hp_dst, rh_dst, cnt_t, bcnt, bcursor, ticket);
    partition_kernel<<<(E_RH + 2047) / 2048, 256, 0, stream>>>(rh_src, rh_dst, bcursor, cnt_s, ebuf, E_RH);
    {
        int n = N_TAXON + N_SOTU;
        int nb = (n + 255) / 256;   // 1172
        scanA_kernel<<<nb, 256, 0, stream>>>(cnt, bsum, n);
        scanB_kernel<<<1, 1024, 0, stream>>>(bsum, nb, row_ptr + n);
        scanC_kernel<<<nb, 256, 0, stream>>>(cnt, bsum, row_ptr, cursor, n);
    }
    fills_kernel<<<2048, 256, 0, stream>>>(hp_src, hp_dst, ebuf, cursor, sorted_all);

    // ---- weight prep (all 7) ----
    wprep_all_kernel<<<(6 * 16384 + 8192 + 255) / 256, 256, 0, stream>>>(
        W1l, W1r, W2l, W2r, W3l, W3r, Wlin, wtbase);

    // ---- triple GEMM: y1, z1, y2 (one x_taxon pass) ----
    gemm3_kernel<<<(N_TAXON + 63) / 64, 256, 0, stream>>>(
        x_taxon, Wt1l, Wt1r, Wt2l, y1, z1, Y23, N_TAXON);

    // ---- z2 = x_sotu @ W2r ----
    gemmS_kernel<<<(N_SOTU + 63) / 64, 256, 0, stream>>>(x_sotu, Wt2r, z2, N_SOTU);

    // ---- fused layer-1 agg + W3l -> Y23 half-b ----
    aggGemm1_kernel<<<N_TAXON / 16, 256, 0, stream>>>(
        y1, row_ptr_t, sorted_all, z1, b1, Wt3l, Y23, N_TAXON);

    // ---- fused rh agg + layer-3 GEMM + final linear -> out ----
    aggGemm23_kernel<<<N_SOTU / 16, 256, 0, stream>>>(
        Y23, row_ptr_s, sorted_all, z2, b2, b3, blin, Wt3r, Wtlin, out, N_SOTU);
}